// Round 9
// baseline (584.219 us; speedup 1.0000x reference)
//
#include <hip/hip_runtime.h>
#include <math.h>

#define NNODES 50000
#define NEDGES 800000
#define NLAYERS 3
#define NHEADS 2
#define NCH 64
#define FDIM 128   // == NHEADS*NCH
#define NCLS 10
#define NGRAPH 64
#define NEG_SLOPE 0.2f
#define GEMMB ((NNODES + 127) / 128)  // 391 blocks, 128 rows/block (32/wave)
#define NB 391                        // buckets = ceil(50000/128)
#define RADB 391                      // radix blocks = ceil(800000/2048)
#define AGGB (NNODES / 4)             // 12500 aggregate blocks

#define WAVE_SYNC()                      \
  do {                                   \
    __builtin_amdgcn_wave_barrier();     \
    __asm__ volatile("" ::: "memory");   \
  } while (0)

typedef __attribute__((ext_vector_type(8))) short bf16x8;
typedef __attribute__((ext_vector_type(4))) float f32x4;

__device__ __forceinline__ unsigned short f2bf(float f) {
  unsigned int u = __builtin_bit_cast(unsigned int, f);
  unsigned int r = u + 0x7FFFu + ((u >> 16) & 1u);  // RNE
  return (unsigned short)(r >> 16);
}
__device__ __forceinline__ float bflo(unsigned v) {
  return __builtin_bit_cast(float, v << 16);
}
__device__ __forceinline__ float bfhi(unsigned v) {
  return __builtin_bit_cast(float, v & 0xFFFF0000u);
}

// ---- W prep (3 blocks) + graph offsets / zero-init (1 block) --------------
__global__ __launch_bounds__(256) void k_wprep(const float* __restrict__ W,
                                               unsigned* __restrict__ Wt,
                                               const int* __restrict__ batch,
                                               int* __restrict__ goff,
                                               float* __restrict__ gsum,
                                               int* __restrict__ bcnt,
                                               int* __restrict__ done) {
  __shared__ float Lt[128][132];
  int l = blockIdx.x;
  int t = threadIdx.x;
  if (l == NLAYERS) {  // goff + zero gsum + zero bcnt + zero done
    if (t < NGRAPH) {
      int lo = 0, hi = NNODES;
      while (lo < hi) {
        int mid = (lo + hi) >> 1;
        if (batch[mid] < t) lo = mid + 1;
        else hi = mid;
      }
      goff[t] = lo;
    }
    if (t == 0) {
      goff[NGRAPH] = NNODES;
      *done = 0;
    }
    for (int i = t; i < NGRAPH * FDIM; i += 256) gsum[i] = 0.f;
    for (int i = t; i < NB; i += 256) bcnt[i] = 0;
    return;
  }
  const float* Wl = W + (size_t)l * FDIM * FDIM;
  unsigned* Wtl = Wt + (size_t)l * FDIM * FDIM / 2;
#pragma unroll
  for (int i = 0; i < 16; ++i) {
    int k = (t >> 5) + 8 * i;
    int n4 = (t & 31) * 4;
    float4 v = *(const float4*)(Wl + (size_t)k * 128 + n4);
    Lt[k][n4 + 0] = v.x;
    Lt[k][n4 + 1] = v.y;
    Lt[k][n4 + 2] = v.z;
    Lt[k][n4 + 3] = v.w;
  }
  __syncthreads();
  int n = t >> 1;
  int kh = (t & 1) * 64;
  for (int kk = 0; kk < 64; kk += 2) {
    unsigned pk = (unsigned)f2bf(Lt[kh + kk][n]) |
                  ((unsigned)f2bf(Lt[kh + kk + 1][n]) << 16);
    Wtl[n * 64 + (kh >> 1) + (kk >> 1)] = pk;
  }
}

// ---------------- MFMA GEMM body (no LDS), M=32 per wave ----------------
// H[row,:] = X[row,:] @ W. Hb dword d of row holds bf16 pair (h0[d], h1[d)).
// Two 16-row M-tiles per wave -> each B fragment load feeds 2 MFMA.
// BF16IN: input rows are pre-rounded bf16 -> direct fragment loads.
template <bool BF16IN>
__device__ __forceinline__ void gemm_body(int blk, const void* __restrict__ Xv,
                                          const unsigned* __restrict__ Wt,
                                          const float* __restrict__ a_sL,
                                          const float* __restrict__ a_dL,
                                          unsigned* __restrict__ Hb,
                                          float* __restrict__ as_,
                                          float* __restrict__ ad_) {
  int t = threadIdx.x;
  int lane = t & 63;
  int w = t >> 6;
  int n16 = lane & 15;
  int quad = lane >> 4;
  int rowb = blk * 128 + w * 32;  // wave's 32-row base

  size_t rb[2];
  rb[0] = (size_t)min(rowb + n16, NNODES - 1) * 128;
  rb[1] = (size_t)min(rowb + 16 + n16, NNODES - 1) * 128;

  f32x4 acc[2][8];
#pragma unroll
  for (int mt = 0; mt < 2; ++mt)
#pragma unroll
    for (int nt = 0; nt < 8; ++nt) {
      f32x4 z = {0.f, 0.f, 0.f, 0.f};
      acc[mt][nt] = z;
    }
#pragma unroll
  for (int kk = 0; kk < 4; ++kk) {
    bf16x8 af[2];
#pragma unroll
    for (int mt = 0; mt < 2; ++mt) {
      if constexpr (BF16IN) {
        const unsigned short* xp = (const unsigned short*)Xv + rb[mt];
        af[mt] = *(const bf16x8*)(xp + kk * 32 + quad * 8);
      } else {
        const float* xp = (const float*)Xv + rb[mt];
        float4 va = *(const float4*)(xp + kk * 32 + quad * 8);
        float4 vb = *(const float4*)(xp + kk * 32 + quad * 8 + 4);
        af[mt][0] = (short)f2bf(va.x); af[mt][1] = (short)f2bf(va.y);
        af[mt][2] = (short)f2bf(va.z); af[mt][3] = (short)f2bf(va.w);
        af[mt][4] = (short)f2bf(vb.x); af[mt][5] = (short)f2bf(vb.y);
        af[mt][6] = (short)f2bf(vb.z); af[mt][7] = (short)f2bf(vb.w);
      }
    }
#pragma unroll
    for (int nt = 0; nt < 8; ++nt) {
      bf16x8 bf = *(const bf16x8*)(Wt + (size_t)(nt * 16 + n16) * 64 +
                                   kk * 16 + quad * 4);
      acc[0][nt] =
          __builtin_amdgcn_mfma_f32_16x16x32_bf16(af[0], bf, acc[0][nt], 0, 0, 0);
      acc[1][nt] =
          __builtin_amdgcn_mfma_f32_16x16x32_bf16(af[1], bf, acc[1][nt], 0, 0, 0);
    }
  }

  float asv[8], adv[8];
#pragma unroll
  for (int nt = 0; nt < 8; ++nt) {
    asv[nt] = a_sL[nt * 16 + n16];
    adv[nt] = a_dL[nt * 16 + n16];
  }
#pragma unroll
  for (int mt = 0; mt < 2; ++mt) {
#pragma unroll
    for (int r = 0; r < 4; ++r) {
      int row = rowb + mt * 16 + quad * 4 + r;
      bool ok = (row < NNODES);
      float ps0 = 0.f, pd0 = 0.f, ps1 = 0.f, pd1 = 0.f;
#pragma unroll
      for (int nt = 0; nt < 4; ++nt) {
        ps0 += acc[mt][nt][r] * asv[nt];
        pd0 += acc[mt][nt][r] * adv[nt];
        ps1 += acc[mt][nt + 4][r] * asv[nt + 4];
        pd1 += acc[mt][nt + 4][r] * adv[nt + 4];
      }
#pragma unroll
      for (int off = 1; off < 16; off <<= 1) {
        ps0 += __shfl_xor(ps0, off, 64);
        pd0 += __shfl_xor(pd0, off, 64);
        ps1 += __shfl_xor(ps1, off, 64);
        pd1 += __shfl_xor(pd1, off, 64);
      }
      if (ok && n16 == 0) {
        as_[row * 2 + 0] = ps0;
        as_[row * 2 + 1] = ps1;
        ad_[row * 2 + 0] = pd0;
        ad_[row * 2 + 1] = pd1;
      }
      if (ok) {
#pragma unroll
        for (int nt = 0; nt < 4; ++nt) {
          unsigned pk = (unsigned)f2bf(acc[mt][nt][r]) |
                        ((unsigned)f2bf(acc[mt][nt + 4][r]) << 16);
          Hb[(size_t)row * 64 + nt * 16 + n16] = pk;
        }
      }
    }
  }
}

__global__ __launch_bounds__(256) void k_gemm(
    const unsigned short* __restrict__ Xh, const unsigned* __restrict__ Wt,
    const float* __restrict__ a_sL, const float* __restrict__ a_dL,
    unsigned* __restrict__ Hb, float* __restrict__ as_,
    float* __restrict__ ad_) {
  gemm_body<true>(blockIdx.x, Xh, Wt, a_sL, a_dL, Hb, as_, ad_);
}

// fused: layer-0 GEMM | radix pass A (LDS hist + return-atomic block bases).
__global__ __launch_bounds__(256) void k_front(
    const float* __restrict__ X, const unsigned* __restrict__ Wt,
    const float* __restrict__ a_sL, const float* __restrict__ a_dL,
    unsigned* __restrict__ Hb, float* __restrict__ as_,
    float* __restrict__ ad_, const int* __restrict__ ei, int* __restrict__ bh,
    int* __restrict__ bcnt) {
  int b = blockIdx.x;
  if (b < GEMMB) {
    gemm_body<false>(b, X, Wt, a_sL, a_dL, Hb, as_, ad_);
  } else {
    __shared__ int hist[NB];
    int blk = b - GEMMB;
    int t = threadIdx.x;
    for (int i = t; i < NB; i += 256) hist[i] = 0;
    __syncthreads();
    int e0 = blk * 2048;
#pragma unroll
    for (int i = 0; i < 8; ++i) {
      int e = e0 + i * 256 + t;
      if (e < NEDGES) atomicAdd(&hist[ei[NEDGES + e] >> 7], 1);
    }
    __syncthreads();
    for (int i = t; i < NB; i += 256) {
      int c = hist[i];
      int base = c ? atomicAdd(&bcnt[i], c) : 0;
      bh[i * RADB + blk] = base;
    }
  }
}

// ---------------- radix pass B (with fused redundant bucket scan) ----------
__global__ __launch_bounds__(256) void k_passB(const int* __restrict__ ei,
                                               const int* __restrict__ bcnt,
                                               const int* __restrict__ bh,
                                               unsigned* __restrict__ ebuf,
                                               int* __restrict__ bstart) {
  __shared__ int curs[NB];
  __shared__ int ps[256];
  int blk = blockIdx.x, t = threadIdx.x;
  int x0 = (2 * t < NB) ? bcnt[2 * t] : 0;
  int x1 = (2 * t + 1 < NB) ? bcnt[2 * t + 1] : 0;
  int pair = x0 + x1;
  ps[t] = pair;
  __syncthreads();
  for (int off = 1; off < 256; off <<= 1) {
    int v = (t >= off) ? ps[t - off] : 0;
    __syncthreads();
    ps[t] += v;
    __syncthreads();
  }
  int ex = ps[t] - pair;
  if (2 * t < NB) {
    curs[2 * t] = ex + bh[(2 * t) * RADB + blk];
    if (blk == 0) bstart[2 * t] = ex;
  }
  if (2 * t + 1 < NB) {
    curs[2 * t + 1] = ex + x0 + bh[(2 * t + 1) * RADB + blk];
    if (blk == 0) bstart[2 * t + 1] = ex + x0;
  }
  if (blk == 0 && t == 0) bstart[NB] = NEDGES;
  __syncthreads();
  int e0 = blk * 2048;
#pragma unroll
  for (int i = 0; i < 8; ++i) {
    int e = e0 + i * 256 + t;
    if (e < NEDGES) {
      int s = ei[e];
      int d = ei[NEDGES + e];
      int pos = atomicAdd(&curs[d >> 7], 1);
      ebuf[pos] = ((unsigned)s << 7) | (unsigned)(d & 127);
    }
  }
}

// ---------------- radix pass C ----------------
__global__ __launch_bounds__(256) void k_passC(const unsigned* __restrict__ ebuf,
                                               const int* __restrict__ bstart,
                                               int* __restrict__ row_ptr,
                                               int* __restrict__ csr) {
  __shared__ int deg[128];
  __shared__ int scn[128];
  int b = blockIdx.x, t = threadIdx.x;
  int node0 = b * 128;
  int nn = min(128, NNODES - node0);
  int estart = bstart[b];
  int eend = bstart[b + 1];
  if (t < 128) deg[t] = 0;
  __syncthreads();
  for (int e = estart + t; e < eend; e += 256)
    atomicAdd(&deg[ebuf[e] & 127], 1);
  __syncthreads();
  if (t < 128) scn[t] = (t < nn) ? deg[t] + 1 : 0;
  __syncthreads();
  for (int off = 1; off < 128; off <<= 1) {
    int v = (t < 128 && t >= off) ? scn[t - off] : 0;
    __syncthreads();
    if (t < 128) scn[t] += v;
    __syncthreads();
  }
  int base = estart + node0;
  if (t < nn) {
    int st = base + (t ? scn[t - 1] : 0);
    row_ptr[node0 + t] = st;
    csr[st] = node0 + t;  // self-loop at rank 0
    deg[t] = st + 1;      // reuse as cursor
  }
  if (b == 0 && t == 0) row_ptr[NNODES] = NEDGES + NNODES;
  __syncthreads();
  for (int e = estart + t; e < eend; e += 256) {
    unsigned v = ebuf[e];
    int pos = atomicAdd(&deg[v & 127], 1);
    csr[pos] = (int)(v >> 7);
  }
}

// One wave per node: softmax + aggregation, software-pipelined gather
// (proven shape: 8-load batches, 1 node/wave, 4 nodes/block).
// Layers 0,1 (XoutH != null): write bf16 rows consumed by the next GEMM.
// Layer 2 (XoutH == null): pool in-place into gsum via atomics, then the
// LAST block (done-ticket) runs the classifier REGISTER-BASED (no extra
// LDS -> no occupancy cost): thread t = (graph t>>2, quarter t&3) partials
// 10 logits over 32 features; shfl_xor(1,2) combine; q==0 lanes softmax.
__global__ __launch_bounds__(256) void k_aggregate(
    const unsigned* __restrict__ Hb, const float* __restrict__ as_,
    const float* __restrict__ ad_, const int* __restrict__ row_ptr,
    const int* __restrict__ csr, const float* __restrict__ bias,
    unsigned short* __restrict__ XoutH, const int* __restrict__ batchp,
    float* __restrict__ gsum, const int* __restrict__ goff,
    const float* __restrict__ lw, const float* __restrict__ lb,
    float* __restrict__ out, int* __restrict__ done) {
  __shared__ float2 wb[4][64];
  __shared__ int sb[4][64];
  __shared__ float outv[4][128];
  __shared__ int gsl[4];
  __shared__ int lastflag;
  int wv = threadIdx.x >> 6;
  int lane = threadIdx.x & 63;
  int node = blockIdx.x * 4 + wv;  // grid*4 == NNODES exactly
  int rs = row_ptr[node], re = row_ptr[node + 1];
  float2 adv = *(const float2*)&ad_[node * 2];
  const unsigned* Hl = Hb + lane;

  float z0 = 0.f, z1 = 0.f, acc0 = 0.f, acc1 = 0.f;
  for (int base = rs; base < re; base += 64) {
    int j = base + lane;
    int s = 0;
    if (j < re) s = csr[j];
    sb[wv][lane] = s;  // slots >= cl carry s=0 (harmless row-0 loads)
    WAVE_SYNC();
    // issue first row batch (8 edges) while the as_ gather flies
    unsigned va[8];
#pragma unroll
    for (int u = 0; u < 8; ++u) va[u] = Hl[(size_t)sb[wv][u] * 64];
    float p0 = 0.f, p1 = 0.f;
    if (j < re) {
      float2 asv = *(const float2*)&as_[s * 2];
      float e0 = asv.x + adv.x; e0 = (e0 > 0.f) ? e0 : NEG_SLOPE * e0;
      float e1 = asv.y + adv.y; e1 = (e1 > 0.f) ? e1 : NEG_SLOPE * e1;
      p0 = __expf(e0);
      p1 = __expf(e1);
    }
    z0 += p0;
    z1 += p1;
    wb[wv][lane] = make_float2(p0, p1);  // slots >= cl carry p=0
    WAVE_SYNC();
    int cl = min(64, re - base);
    int cl8 = (cl + 7) & ~7;  // zero-padded to batch multiple
    int jj = 8;
    for (; jj < cl8; jj += 8) {
      unsigned vb2[8];
#pragma unroll
      for (int u = 0; u < 8; ++u) vb2[u] = Hl[(size_t)sb[wv][jj + u] * 64];
#pragma unroll
      for (int u = 0; u < 8; ++u) {
        float2 w = wb[wv][jj - 8 + u];
        acc0 += w.x * bflo(va[u]);
        acc1 += w.y * bfhi(va[u]);
      }
#pragma unroll
      for (int u = 0; u < 8; ++u) va[u] = vb2[u];
    }
#pragma unroll
    for (int u = 0; u < 8; ++u) {
      float2 w = wb[wv][jj - 8 + u];
      acc0 += w.x * bflo(va[u]);
      acc1 += w.y * bfhi(va[u]);
    }
    WAVE_SYNC();
  }
#pragma unroll
  for (int off = 32; off > 0; off >>= 1) {
    z0 += __shfl_xor(z0, off, 64);
    z1 += __shfl_xor(z1, off, 64);
  }
  float o0 = acc0 / z0 + bias[lane];
  float o1 = acc1 / z1 + bias[64 + lane];
  o0 = (o0 > 0.f) ? o0 : expm1f(o0);  // ELU
  o1 = (o1 > 0.f) ? o1 : expm1f(o1);
  if (XoutH) {
    XoutH[(size_t)node * 128 + lane] = f2bf(o0);
    XoutH[(size_t)node * 128 + 64 + lane] = f2bf(o1);
    return;
  }
  // ---- layer 2: in-place pool ----
  outv[wv][lane] = o0;
  outv[wv][64 + lane] = o1;
  if (lane == 0) gsl[wv] = batchp[node];
  __syncthreads();
  if (threadIdx.x < 128) {
    int c = threadIdx.x;
    float acc = outv[0][c];
    int gcur = gsl[0];
#pragma unroll
    for (int w2 = 1; w2 < 4; ++w2) {
      if (gsl[w2] == gcur) {
        acc += outv[w2][c];
      } else {
        atomicAdd(&gsum[gcur * FDIM + c], acc);
        gcur = gsl[w2];
        acc = outv[w2][c];
      }
    }
    atomicAdd(&gsum[gcur * FDIM + c], acc);
  }
  __syncthreads();  // drains the atomics before the ticket
  if (threadIdx.x == 0) {
    __threadfence();
    int prev = atomicAdd(done, 1);
    lastflag = (prev == AGGB - 1) ? 1 : 0;
  }
  __syncthreads();
  if (!lastflag) return;
  // ---- last block: register-based classifier ----
  __threadfence();
  int t = threadIdx.x;
  int g2 = t >> 2, q = t & 3;  // 64 graphs x 4 feature-quarters
  float cnt = (float)(goff[g2 + 1] - goff[g2]);
  float inv = 1.f / fmaxf(cnt, 1.f);
  float lg[NCLS];
#pragma unroll
  for (int k = 0; k < NCLS; ++k) lg[k] = (q == 0) ? lb[k] : 0.f;
  int f0 = q * 32;
  for (int i = 0; i < 32; ++i) {
    float pv = gsum[g2 * FDIM + f0 + i] * inv;
#pragma unroll
    for (int k = 0; k < NCLS; ++k) lg[k] += pv * lw[(f0 + i) * NCLS + k];
  }
#pragma unroll
  for (int off = 1; off < 4; off <<= 1) {
#pragma unroll
    for (int k = 0; k < NCLS; ++k) lg[k] += __shfl_xor(lg[k], off, 64);
  }
  if (q == 0) {
    float mx = lg[0];
#pragma unroll
    for (int k = 1; k < NCLS; ++k) mx = fmaxf(mx, lg[k]);
    float ssum = 0.f;
#pragma unroll
    for (int k = 0; k < NCLS; ++k) {
      lg[k] = expf(lg[k] - mx);
      ssum += lg[k];
    }
    float invs = 1.f / ssum;
#pragma unroll
    for (int k = 0; k < NCLS; ++k) out[g2 * NCLS + k] = lg[k] * invs;
  }
}

// ---------------- launch ----------------

extern "C" void kernel_launch(void* const* d_in, const int* in_sizes, int n_in,
                              void* d_out, int out_size, void* d_ws,
                              size_t ws_size, hipStream_t stream) {
  const float* x = (const float*)d_in[0];
  const int* ei = (const int*)d_in[1];
  const int* batch = (const int*)d_in[2];
  const float* W = (const float*)d_in[3];
  const float* a_s = (const float*)d_in[4];
  const float* a_d = (const float*)d_in[5];
  const float* bias = (const float*)d_in[6];
  const float* lw = (const float*)d_in[7];
  const float* lb = (const float*)d_in[8];
  float* out = (float*)d_out;

  unsigned* Hb = (unsigned*)d_ws;                  // N*64 packed bf16 pairs
  float* xb = (float*)(Hb + (size_t)NNODES * 64);  // N*128 (unused spare)
  float* as_ = xb + (size_t)NNODES * 128;          // N*2
  float* ad_ = as_ + (size_t)NNODES * 2;           // N*2
  float* gsum = ad_ + (size_t)NNODES * 2;          // 64*128
  int* goff = (int*)(gsum + NGRAPH * FDIM);        // 65
  int* bcnt = goff + (NGRAPH + 1);                 // NB
  int* bstart = bcnt + NB;                         // NB+1
  int* row_ptr = bstart + (NB + 1);                // N+1
  int* csr = row_ptr + (NNODES + 1);               // E+N
  int* bh = csr + (NEDGES + NNODES);               // NB*RADB
  unsigned* ebuf = (unsigned*)(bh + NB * RADB);    // E (+pad)
  unsigned* Wt = ebuf + (NEDGES + 1024);           // 3*8192 (bf16 W^T)
  unsigned short* xbh = (unsigned short*)(Wt + 3 * 8192);  // N*128 bf16
  int* done = (int*)(xbh + (size_t)NNODES * 128);  // 1

  k_wprep<<<NLAYERS + 1, 256, 0, stream>>>(W, Wt, batch, goff, gsum, bcnt,
                                           done);
  // layer-0 GEMM overlapped with radix pass A
  k_front<<<GEMMB + RADB, 256, 0, stream>>>(x, Wt, a_s, a_d, Hb, as_, ad_, ei,
                                            bh, bcnt);
  k_passB<<<RADB, 256, 0, stream>>>(ei, bcnt, bh, ebuf, bstart);
  k_passC<<<NB, 256, 0, stream>>>(ebuf, bstart, row_ptr, csr);

  for (int l = 0; l < NLAYERS; ++l) {
    if (l > 0) {
      k_gemm<<<GEMMB, 256, 0, stream>>>(xbh, Wt + (size_t)l * FDIM * FDIM / 2,
                                        a_s + l * FDIM, a_d + l * FDIM, Hb,
                                        as_, ad_);
    }
    unsigned short* oh = (l < NLAYERS - 1) ? xbh : nullptr;
    const int* bp = (l == NLAYERS - 1) ? batch : nullptr;
    k_aggregate<<<AGGB, 256, 0, stream>>>(Hb, as_, ad_, row_ptr, csr,
                                          bias + l * FDIM, oh, bp, gsum, goff,
                                          lw, lb, out, done);
  }
}

// Round 10
// 286.132 us; speedup vs baseline: 2.0418x; 2.0418x over previous
//
#include <hip/hip_runtime.h>
#include <math.h>

#define NNODES 50000
#define NEDGES 800000
#define NLAYERS 3
#define NHEADS 2
#define NCH 64
#define FDIM 128   // == NHEADS*NCH
#define NCLS 10
#define NGRAPH 64
#define NEG_SLOPE 0.2f
#define GEMMB ((NNODES + 127) / 128)  // 391 blocks, 128 rows/block (32/wave)
#define NB 391                        // buckets = ceil(50000/128)
#define RADB 391                      // radix blocks = ceil(800000/2048)

#define WAVE_SYNC()                      \
  do {                                   \
    __builtin_amdgcn_wave_barrier();     \
    __asm__ volatile("" ::: "memory");   \
  } while (0)

typedef __attribute__((ext_vector_type(8))) short bf16x8;
typedef __attribute__((ext_vector_type(4))) float f32x4;

__device__ __forceinline__ unsigned short f2bf(float f) {
  unsigned int u = __builtin_bit_cast(unsigned int, f);
  unsigned int r = u + 0x7FFFu + ((u >> 16) & 1u);  // RNE
  return (unsigned short)(r >> 16);
}
__device__ __forceinline__ float bflo(unsigned v) {
  return __builtin_bit_cast(float, v << 16);
}
__device__ __forceinline__ float bfhi(unsigned v) {
  return __builtin_bit_cast(float, v & 0xFFFF0000u);
}

// ---- W prep (3 blocks) + graph offsets / zero-init (1 block) --------------
__global__ __launch_bounds__(256) void k_wprep(const float* __restrict__ W,
                                               unsigned* __restrict__ Wt,
                                               const int* __restrict__ batch,
                                               int* __restrict__ goff,
                                               float* __restrict__ gsum,
                                               int* __restrict__ bcnt) {
  __shared__ float Lt[128][132];
  int l = blockIdx.x;
  int t = threadIdx.x;
  if (l == NLAYERS) {  // goff + zero gsum + zero bcnt
    if (t < NGRAPH) {
      int lo = 0, hi = NNODES;
      while (lo < hi) {
        int mid = (lo + hi) >> 1;
        if (batch[mid] < t) lo = mid + 1;
        else hi = mid;
      }
      goff[t] = lo;
    }
    if (t == 0) goff[NGRAPH] = NNODES;
    for (int i = t; i < NGRAPH * FDIM; i += 256) gsum[i] = 0.f;
    for (int i = t; i < NB; i += 256) bcnt[i] = 0;
    return;
  }
  const float* Wl = W + (size_t)l * FDIM * FDIM;
  unsigned* Wtl = Wt + (size_t)l * FDIM * FDIM / 2;
#pragma unroll
  for (int i = 0; i < 16; ++i) {
    int k = (t >> 5) + 8 * i;
    int n4 = (t & 31) * 4;
    float4 v = *(const float4*)(Wl + (size_t)k * 128 + n4);
    Lt[k][n4 + 0] = v.x;
    Lt[k][n4 + 1] = v.y;
    Lt[k][n4 + 2] = v.z;
    Lt[k][n4 + 3] = v.w;
  }
  __syncthreads();
  int n = t >> 1;
  int kh = (t & 1) * 64;
  for (int kk = 0; kk < 64; kk += 2) {
    unsigned pk = (unsigned)f2bf(Lt[kh + kk][n]) |
                  ((unsigned)f2bf(Lt[kh + kk + 1][n]) << 16);
    Wtl[n * 64 + (kh >> 1) + (kk >> 1)] = pk;
  }
}

// ---------------- MFMA GEMM body (no LDS), M=32 per wave ----------------
// H[row,:] = X[row,:] @ W. Hb dword d of row holds bf16 pair (h0[d], h1[d)).
// Two 16-row M-tiles per wave -> each B fragment load feeds 2 MFMA.
// BF16IN: input rows are pre-rounded bf16 -> direct fragment loads.
template <bool BF16IN>
__device__ __forceinline__ void gemm_body(int blk, const void* __restrict__ Xv,
                                          const unsigned* __restrict__ Wt,
                                          const float* __restrict__ a_sL,
                                          const float* __restrict__ a_dL,
                                          unsigned* __restrict__ Hb,
                                          float* __restrict__ as_,
                                          float* __restrict__ ad_) {
  int t = threadIdx.x;
  int lane = t & 63;
  int w = t >> 6;
  int n16 = lane & 15;
  int quad = lane >> 4;
  int rowb = blk * 128 + w * 32;  // wave's 32-row base

  size_t rb[2];
  rb[0] = (size_t)min(rowb + n16, NNODES - 1) * 128;
  rb[1] = (size_t)min(rowb + 16 + n16, NNODES - 1) * 128;

  f32x4 acc[2][8];
#pragma unroll
  for (int mt = 0; mt < 2; ++mt)
#pragma unroll
    for (int nt = 0; nt < 8; ++nt) {
      f32x4 z = {0.f, 0.f, 0.f, 0.f};
      acc[mt][nt] = z;
    }
#pragma unroll
  for (int kk = 0; kk < 4; ++kk) {
    bf16x8 af[2];
#pragma unroll
    for (int mt = 0; mt < 2; ++mt) {
      if constexpr (BF16IN) {
        const unsigned short* xp = (const unsigned short*)Xv + rb[mt];
        af[mt] = *(const bf16x8*)(xp + kk * 32 + quad * 8);
      } else {
        const float* xp = (const float*)Xv + rb[mt];
        float4 va = *(const float4*)(xp + kk * 32 + quad * 8);
        float4 vb = *(const float4*)(xp + kk * 32 + quad * 8 + 4);
        af[mt][0] = (short)f2bf(va.x); af[mt][1] = (short)f2bf(va.y);
        af[mt][2] = (short)f2bf(va.z); af[mt][3] = (short)f2bf(va.w);
        af[mt][4] = (short)f2bf(vb.x); af[mt][5] = (short)f2bf(vb.y);
        af[mt][6] = (short)f2bf(vb.z); af[mt][7] = (short)f2bf(vb.w);
      }
    }
#pragma unroll
    for (int nt = 0; nt < 8; ++nt) {
      bf16x8 bf = *(const bf16x8*)(Wt + (size_t)(nt * 16 + n16) * 64 +
                                   kk * 16 + quad * 4);
      acc[0][nt] =
          __builtin_amdgcn_mfma_f32_16x16x32_bf16(af[0], bf, acc[0][nt], 0, 0, 0);
      acc[1][nt] =
          __builtin_amdgcn_mfma_f32_16x16x32_bf16(af[1], bf, acc[1][nt], 0, 0, 0);
    }
  }

  float asv[8], adv[8];
#pragma unroll
  for (int nt = 0; nt < 8; ++nt) {
    asv[nt] = a_sL[nt * 16 + n16];
    adv[nt] = a_dL[nt * 16 + n16];
  }
#pragma unroll
  for (int mt = 0; mt < 2; ++mt) {
#pragma unroll
    for (int r = 0; r < 4; ++r) {
      int row = rowb + mt * 16 + quad * 4 + r;
      bool ok = (row < NNODES);
      float ps0 = 0.f, pd0 = 0.f, ps1 = 0.f, pd1 = 0.f;
#pragma unroll
      for (int nt = 0; nt < 4; ++nt) {
        ps0 += acc[mt][nt][r] * asv[nt];
        pd0 += acc[mt][nt][r] * adv[nt];
        ps1 += acc[mt][nt + 4][r] * asv[nt + 4];
        pd1 += acc[mt][nt + 4][r] * adv[nt + 4];
      }
#pragma unroll
      for (int off = 1; off < 16; off <<= 1) {
        ps0 += __shfl_xor(ps0, off, 64);
        pd0 += __shfl_xor(pd0, off, 64);
        ps1 += __shfl_xor(ps1, off, 64);
        pd1 += __shfl_xor(pd1, off, 64);
      }
      if (ok && n16 == 0) {
        as_[row * 2 + 0] = ps0;
        as_[row * 2 + 1] = ps1;
        ad_[row * 2 + 0] = pd0;
        ad_[row * 2 + 1] = pd1;
      }
      if (ok) {
#pragma unroll
        for (int nt = 0; nt < 4; ++nt) {
          unsigned pk = (unsigned)f2bf(acc[mt][nt][r]) |
                        ((unsigned)f2bf(acc[mt][nt + 4][r]) << 16);
          Hb[(size_t)row * 64 + nt * 16 + n16] = pk;
        }
      }
    }
  }
}

__global__ __launch_bounds__(256) void k_gemm(
    const unsigned short* __restrict__ Xh, const unsigned* __restrict__ Wt,
    const float* __restrict__ a_sL, const float* __restrict__ a_dL,
    unsigned* __restrict__ Hb, float* __restrict__ as_,
    float* __restrict__ ad_) {
  gemm_body<true>(blockIdx.x, Xh, Wt, a_sL, a_dL, Hb, as_, ad_);
}

// fused: layer-0 GEMM | radix pass A (LDS hist + return-atomic block bases).
__global__ __launch_bounds__(256) void k_front(
    const float* __restrict__ X, const unsigned* __restrict__ Wt,
    const float* __restrict__ a_sL, const float* __restrict__ a_dL,
    unsigned* __restrict__ Hb, float* __restrict__ as_,
    float* __restrict__ ad_, const int* __restrict__ ei, int* __restrict__ bh,
    int* __restrict__ bcnt) {
  int b = blockIdx.x;
  if (b < GEMMB) {
    gemm_body<false>(b, X, Wt, a_sL, a_dL, Hb, as_, ad_);
  } else {
    __shared__ int hist[NB];
    int blk = b - GEMMB;
    int t = threadIdx.x;
    for (int i = t; i < NB; i += 256) hist[i] = 0;
    __syncthreads();
    int e0 = blk * 2048;
#pragma unroll
    for (int i = 0; i < 8; ++i) {
      int e = e0 + i * 256 + t;
      if (e < NEDGES) atomicAdd(&hist[ei[NEDGES + e] >> 7], 1);
    }
    __syncthreads();
    for (int i = t; i < NB; i += 256) {
      int c = hist[i];
      int base = c ? atomicAdd(&bcnt[i], c) : 0;
      bh[i * RADB + blk] = base;
    }
  }
}

// ---------------- radix pass B (with fused redundant bucket scan) ----------
__global__ __launch_bounds__(256) void k_passB(const int* __restrict__ ei,
                                               const int* __restrict__ bcnt,
                                               const int* __restrict__ bh,
                                               unsigned* __restrict__ ebuf,
                                               int* __restrict__ bstart) {
  __shared__ int curs[NB];
  __shared__ int ps[256];
  int blk = blockIdx.x, t = threadIdx.x;
  int x0 = (2 * t < NB) ? bcnt[2 * t] : 0;
  int x1 = (2 * t + 1 < NB) ? bcnt[2 * t + 1] : 0;
  int pair = x0 + x1;
  ps[t] = pair;
  __syncthreads();
  for (int off = 1; off < 256; off <<= 1) {
    int v = (t >= off) ? ps[t - off] : 0;
    __syncthreads();
    ps[t] += v;
    __syncthreads();
  }
  int ex = ps[t] - pair;
  if (2 * t < NB) {
    curs[2 * t] = ex + bh[(2 * t) * RADB + blk];
    if (blk == 0) bstart[2 * t] = ex;
  }
  if (2 * t + 1 < NB) {
    curs[2 * t + 1] = ex + x0 + bh[(2 * t + 1) * RADB + blk];
    if (blk == 0) bstart[2 * t + 1] = ex + x0;
  }
  if (blk == 0 && t == 0) bstart[NB] = NEDGES;
  __syncthreads();
  int e0 = blk * 2048;
#pragma unroll
  for (int i = 0; i < 8; ++i) {
    int e = e0 + i * 256 + t;
    if (e < NEDGES) {
      int s = ei[e];
      int d = ei[NEDGES + e];
      int pos = atomicAdd(&curs[d >> 7], 1);
      ebuf[pos] = ((unsigned)s << 7) | (unsigned)(d & 127);
    }
  }
}

// ---------------- radix pass C ----------------
__global__ __launch_bounds__(256) void k_passC(const unsigned* __restrict__ ebuf,
                                               const int* __restrict__ bstart,
                                               int* __restrict__ row_ptr,
                                               int* __restrict__ csr) {
  __shared__ int deg[128];
  __shared__ int scn[128];
  int b = blockIdx.x, t = threadIdx.x;
  int node0 = b * 128;
  int nn = min(128, NNODES - node0);
  int estart = bstart[b];
  int eend = bstart[b + 1];
  if (t < 128) deg[t] = 0;
  __syncthreads();
  for (int e = estart + t; e < eend; e += 256)
    atomicAdd(&deg[ebuf[e] & 127], 1);
  __syncthreads();
  if (t < 128) scn[t] = (t < nn) ? deg[t] + 1 : 0;
  __syncthreads();
  for (int off = 1; off < 128; off <<= 1) {
    int v = (t < 128 && t >= off) ? scn[t - off] : 0;
    __syncthreads();
    if (t < 128) scn[t] += v;
    __syncthreads();
  }
  int base = estart + node0;
  if (t < nn) {
    int st = base + (t ? scn[t - 1] : 0);
    row_ptr[node0 + t] = st;
    csr[st] = node0 + t;  // self-loop at rank 0
    deg[t] = st + 1;      // reuse as cursor
  }
  if (b == 0 && t == 0) row_ptr[NNODES] = NEDGES + NNODES;
  __syncthreads();
  for (int e = estart + t; e < eend; e += 256) {
    unsigned v = ebuf[e];
    int pos = atomicAdd(&deg[v & 127], 1);
    csr[pos] = (int)(v >> 7);
  }
}

// One wave per node: softmax + aggregation, software-pipelined gather
// (round-6 proven shape: 8-load batches, 1 node/wave, 4 nodes/block).
// Layers 0,1 (XoutH != null): write bf16 rows consumed by the next GEMM.
// Layer 2 (XoutH == null): POOL IN-PLACE -- waves stage their 128 outputs in
// LDS, a 128-thread pass reduces the block's (graph-sorted, <=2 distinct
// graphs) nodes and emits 128 atomics/block into gsum. Deletes the 25.6MB
// xb write + k_pool2's 25.6MB re-read.
__global__ __launch_bounds__(256) void k_aggregate(
    const unsigned* __restrict__ Hb, const float* __restrict__ as_,
    const float* __restrict__ ad_, const int* __restrict__ row_ptr,
    const int* __restrict__ csr, const float* __restrict__ bias,
    unsigned short* __restrict__ XoutH, const int* __restrict__ batchp,
    float* __restrict__ gsum) {
  __shared__ float2 wb[4][64];
  __shared__ int sb[4][64];
  __shared__ float outv[4][128];
  __shared__ int gsl[4];
  int wv = threadIdx.x >> 6;
  int lane = threadIdx.x & 63;
  int node = blockIdx.x * 4 + wv;  // grid*4 == NNODES exactly
  int rs = row_ptr[node], re = row_ptr[node + 1];
  float2 adv = *(const float2*)&ad_[node * 2];
  const unsigned* Hl = Hb + lane;

  float z0 = 0.f, z1 = 0.f, acc0 = 0.f, acc1 = 0.f;
  for (int base = rs; base < re; base += 64) {
    int j = base + lane;
    int s = 0;
    if (j < re) s = csr[j];
    sb[wv][lane] = s;  // slots >= cl carry s=0 (harmless row-0 loads)
    WAVE_SYNC();
    // issue first row batch (8 edges) while the as_ gather flies
    unsigned va[8];
#pragma unroll
    for (int u = 0; u < 8; ++u) va[u] = Hl[(size_t)sb[wv][u] * 64];
    float p0 = 0.f, p1 = 0.f;
    if (j < re) {
      float2 asv = *(const float2*)&as_[s * 2];
      float e0 = asv.x + adv.x; e0 = (e0 > 0.f) ? e0 : NEG_SLOPE * e0;
      float e1 = asv.y + adv.y; e1 = (e1 > 0.f) ? e1 : NEG_SLOPE * e1;
      p0 = __expf(e0);
      p1 = __expf(e1);
    }
    z0 += p0;
    z1 += p1;
    wb[wv][lane] = make_float2(p0, p1);  // slots >= cl carry p=0
    WAVE_SYNC();
    int cl = min(64, re - base);
    int cl8 = (cl + 7) & ~7;  // zero-padded to batch multiple
    int jj = 8;
    for (; jj < cl8; jj += 8) {
      unsigned vb2[8];
#pragma unroll
      for (int u = 0; u < 8; ++u) vb2[u] = Hl[(size_t)sb[wv][jj + u] * 64];
#pragma unroll
      for (int u = 0; u < 8; ++u) {
        float2 w = wb[wv][jj - 8 + u];
        acc0 += w.x * bflo(va[u]);
        acc1 += w.y * bfhi(va[u]);
      }
#pragma unroll
      for (int u = 0; u < 8; ++u) va[u] = vb2[u];
    }
#pragma unroll
    for (int u = 0; u < 8; ++u) {
      float2 w = wb[wv][jj - 8 + u];
      acc0 += w.x * bflo(va[u]);
      acc1 += w.y * bfhi(va[u]);
    }
    WAVE_SYNC();
  }
#pragma unroll
  for (int off = 32; off > 0; off >>= 1) {
    z0 += __shfl_xor(z0, off, 64);
    z1 += __shfl_xor(z1, off, 64);
  }
  float o0 = acc0 / z0 + bias[lane];
  float o1 = acc1 / z1 + bias[64 + lane];
  o0 = (o0 > 0.f) ? o0 : expm1f(o0);  // ELU
  o1 = (o1 > 0.f) ? o1 : expm1f(o1);
  if (XoutH) {
    XoutH[(size_t)node * 128 + lane] = f2bf(o0);
    XoutH[(size_t)node * 128 + 64 + lane] = f2bf(o1);
  } else {
    outv[wv][lane] = o0;
    outv[wv][64 + lane] = o1;
    if (lane == 0) gsl[wv] = batchp[node];
    __syncthreads();
    if (threadIdx.x < 128) {
      int c = threadIdx.x;
      float acc = outv[0][c];
      int gcur = gsl[0];
#pragma unroll
      for (int w2 = 1; w2 < 4; ++w2) {
        if (gsl[w2] == gcur) {
          acc += outv[w2][c];
        } else {
          atomicAdd(&gsum[gcur * FDIM + c], acc);
          gcur = gsl[w2];
          acc = outv[w2][c];
        }
      }
      atomicAdd(&gsum[gcur * FDIM + c], acc);
    }
  }
}

// ---------------- classifier (1 block; coalesced LDS stage of gsum) --------
__global__ __launch_bounds__(256) void k_final(const float* __restrict__ gsum,
                                               const int* __restrict__ goff,
                                               const float* __restrict__ lw,
                                               const float* __restrict__ lb,
                                               float* __restrict__ out) {
  __shared__ float sg[NGRAPH * 132];  // padded stride vs bank conflicts
  int t = threadIdx.x;
  for (int i = t; i < NGRAPH * FDIM; i += 256)
    sg[(i >> 7) * 132 + (i & 127)] = gsum[i];
  __syncthreads();
  if (t < NGRAPH) {
    int g2 = t;
    float cnt = (float)(goff[g2 + 1] - goff[g2]);
    float inv = 1.f / fmaxf(cnt, 1.f);
    float lg[NCLS];
#pragma unroll
    for (int k = 0; k < NCLS; ++k) lg[k] = lb[k];
    for (int cc = 0; cc < FDIM; ++cc) {
      float pv = sg[g2 * 132 + cc] * inv;
#pragma unroll
      for (int k = 0; k < NCLS; ++k) lg[k] += pv * lw[cc * NCLS + k];
    }
    float mx = lg[0];
#pragma unroll
    for (int k = 1; k < NCLS; ++k) mx = fmaxf(mx, lg[k]);
    float ssum = 0.f;
#pragma unroll
    for (int k = 0; k < NCLS; ++k) {
      lg[k] = expf(lg[k] - mx);
      ssum += lg[k];
    }
    float invs = 1.f / ssum;
#pragma unroll
    for (int k = 0; k < NCLS; ++k) out[g2 * NCLS + k] = lg[k] * invs;
  }
}

// ---------------- launch ----------------

extern "C" void kernel_launch(void* const* d_in, const int* in_sizes, int n_in,
                              void* d_out, int out_size, void* d_ws,
                              size_t ws_size, hipStream_t stream) {
  const float* x = (const float*)d_in[0];
  const int* ei = (const int*)d_in[1];
  const int* batch = (const int*)d_in[2];
  const float* W = (const float*)d_in[3];
  const float* a_s = (const float*)d_in[4];
  const float* a_d = (const float*)d_in[5];
  const float* bias = (const float*)d_in[6];
  const float* lw = (const float*)d_in[7];
  const float* lb = (const float*)d_in[8];
  float* out = (float*)d_out;

  unsigned* Hb = (unsigned*)d_ws;                  // N*64 packed bf16 pairs
  float* xb = (float*)(Hb + (size_t)NNODES * 64);  // N*128 (unused spare)
  float* as_ = xb + (size_t)NNODES * 128;          // N*2
  float* ad_ = as_ + (size_t)NNODES * 2;           // N*2
  float* gsum = ad_ + (size_t)NNODES * 2;          // 64*128
  int* goff = (int*)(gsum + NGRAPH * FDIM);        // 65
  int* bcnt = goff + (NGRAPH + 1);                 // NB
  int* bstart = bcnt + NB;                         // NB+1
  int* row_ptr = bstart + (NB + 1);                // N+1
  int* csr = row_ptr + (NNODES + 1);               // E+N
  int* bh = csr + (NEDGES + NNODES);               // NB*RADB
  unsigned* ebuf = (unsigned*)(bh + NB * RADB);    // E (+pad)
  unsigned* Wt = ebuf + (NEDGES + 1024);           // 3*8192 (bf16 W^T)
  unsigned short* xbh = (unsigned short*)(Wt + 3 * 8192);  // N*128 bf16

  k_wprep<<<NLAYERS + 1, 256, 0, stream>>>(W, Wt, batch, goff, gsum, bcnt);
  // layer-0 GEMM overlapped with radix pass A
  k_front<<<GEMMB + RADB, 256, 0, stream>>>(x, Wt, a_s, a_d, Hb, as_, ad_, ei,
                                            bh, bcnt);
  k_passB<<<RADB, 256, 0, stream>>>(ei, bcnt, bh, ebuf, bstart);
  k_passC<<<NB, 256, 0, stream>>>(ebuf, bstart, row_ptr, csr);

  for (int l = 0; l < NLAYERS; ++l) {
    if (l > 0) {
      k_gemm<<<GEMMB, 256, 0, stream>>>(xbh, Wt + (size_t)l * FDIM * FDIM / 2,
                                        a_s + l * FDIM, a_d + l * FDIM, Hb,
                                        as_, ad_);
    }
    unsigned short* oh = (l < NLAYERS - 1) ? xbh : nullptr;
    const int* bp = (l == NLAYERS - 1) ? batch : nullptr;
    k_aggregate<<<NNODES / 4, 256, 0, stream>>>(Hb, as_, ad_, row_ptr, csr,
                                                bias + l * FDIM, oh, bp, gsum);
  }
  k_final<<<1, 256, 0, stream>>>(gsum, goff, lw, lb, out);
}